// Round 2
// baseline (105.134 us; speedup 1.0000x reference)
//
#include <hip/hip_runtime.h>
#include <stdint.h>

// dist[b, tails[e]] += ew[e] where heads[e]==batch[b,0,0] && etype[e]==batch[b,0,2],
// then row-softmax over N=50000. B=64, E=1e6. Expected matches ~5 total ->
// sparse softmax: M_b = max(0, max v), S_b = (N-nnz_b)*exp(-M) + sum exp(v-M),
// unmatched outputs = exp(-M_b)/S_b (row constant), matched fixed up after.

#define B_MAX 64

// ---------------- scatter: 4 edges/thread, LDS bloom filter over 64 keys ------------
__global__ __launch_bounds__(256)
void scatter_kernel(const int* __restrict__ heads,
                    const int* __restrict__ tails,
                    const int* __restrict__ etype,
                    const float* __restrict__ ew,
                    const int* __restrict__ batch,
                    float* __restrict__ dist,     // (B,N) in ws, pre-zeroed
                    int* __restrict__ cnt,        // in ws, pre-zeroed
                    int2* __restrict__ list,      // in ws, (b, tail) first-touch pairs
                    int E, int N, int B, int listCap) {
    __shared__ unsigned s_keys[B_MAX];
    __shared__ unsigned s_bloom[128];            // 4096-bit bloom
    if (threadIdx.x < 128) s_bloom[threadIdx.x] = 0u;
    __syncthreads();
    if (threadIdx.x < B) {
        unsigned h = (unsigned)batch[threadIdx.x * 96 + 0];   // batch[b,0,0]
        unsigned r = (unsigned)batch[threadIdx.x * 96 + 2];   // batch[b,0,2]
        unsigned key = (h << 16) | (r & 0xFFFFu);             // h<65536, r<65536
        s_keys[threadIdx.x] = key;
        unsigned hsh = (key * 0x9E3779B1u) >> 20;             // 12-bit hash
        atomicOr(&s_bloom[hsh >> 5], 1u << (hsh & 31));
    }
    __syncthreads();

    int base = (blockIdx.x * blockDim.x + threadIdx.x) * 4;
    if (base >= E) return;

    int h4[4], t4[4];
    if (base + 3 < E) {
        int4 hv = ((const int4*)heads)[base >> 2];
        int4 tv = ((const int4*)etype)[base >> 2];
        h4[0] = hv.x; h4[1] = hv.y; h4[2] = hv.z; h4[3] = hv.w;
        t4[0] = tv.x; t4[1] = tv.y; t4[2] = tv.z; t4[3] = tv.w;
    } else {
        for (int j = 0; j < 4; ++j) {
            int e = base + j;
            h4[j] = (e < E) ? heads[e] : -1;
            t4[j] = (e < E) ? etype[e] : -1;
        }
    }
#pragma unroll
    for (int j = 0; j < 4; ++j) {
        int e = base + j;
        if (e >= E) break;
        unsigned key = ((unsigned)h4[j] << 16) | ((unsigned)t4[j] & 0xFFFFu);
        unsigned hsh = (key * 0x9E3779B1u) >> 20;
        if (!(s_bloom[hsh >> 5] & (1u << (hsh & 31)))) continue;   // ~98.4% exit here
        int tail = -1; float w = 0.0f;
        for (int b = 0; b < B; ++b) {
            if (s_keys[b] == key) {
                if (tail < 0) { tail = tails[e]; w = ew[e]; }
                float old = atomicAdd(dist + (size_t)b * N + tail, w);
                if (old == 0.0f) {                  // first toucher appends (b,tail)
                    int pos = atomicAdd(cnt, 1);
                    if (pos < listCap) list[pos] = make_int2(b, tail);
                }
            }
        }
    }
}

// ---------------- stats: one block; M_b, nnz_b, S_b over the sparse list ------------
// stats layout: [0..B) = M_b, [B..2B) = 1/S_b, [2B..3B) = exp(-M_b)/S_b
__global__ __launch_bounds__(256)
void stats_kernel(const float* __restrict__ dist,
                  const int* __restrict__ cnt,
                  const int2* __restrict__ list,
                  float* __restrict__ stats,
                  int N, int B, int listCap) {
    __shared__ unsigned sM[B_MAX];   // float-as-uint max (values >= 0)
    __shared__ int sCnt[B_MAX];
    __shared__ float sS[B_MAX];
    int tid = threadIdx.x;
    if (tid < B) { sM[tid] = 0u; sCnt[tid] = 0; sS[tid] = 0.0f; }
    __syncthreads();
    int n = min(*cnt, listCap);
    for (int i = tid; i < n; i += blockDim.x) {
        int2 p = list[i];
        float v = dist[(size_t)p.x * N + p.y];
        atomicMax(&sM[p.x], __float_as_uint(v));  // v >= 0 -> uint order == float order
        atomicAdd(&sCnt[p.x], 1);
    }
    __syncthreads();
    for (int i = tid; i < n; i += blockDim.x) {
        int2 p = list[i];
        float v = dist[(size_t)p.x * N + p.y];
        atomicAdd(&sS[p.x], __expf(v - __uint_as_float(sM[p.x])));
    }
    __syncthreads();
    if (tid < B) {
        float M = __uint_as_float(sM[tid]);
        float em = __expf(-M);
        float S = (float)(N - sCnt[tid]) * em + sS[tid];
        float inv = 1.0f / S;
        stats[tid]         = M;
        stats[B + tid]     = inv;
        stats[2 * B + tid] = em * inv;   // row baseline value
    }
}

// ---------------- fill: out[b,:] = baseline_b, float4 stores ------------------------
__global__ __launch_bounds__(256)
void fill_kernel(float* __restrict__ out, const float* __restrict__ stats,
                 int N4, int B) {
    int b = blockIdx.y;
    float base = stats[2 * B + b];
    int i = blockIdx.x * blockDim.x + threadIdx.x;
    if (i < N4) {
        float4 v = make_float4(base, base, base, base);
        ((float4*)(out + (size_t)b * (size_t)N4 * 4))[i] = v;
    }
}

// ---------------- fixup: matched cells + scalar tail + ALPHA ------------------------
__global__ __launch_bounds__(256)
void fixup_kernel(float* __restrict__ out, const float* __restrict__ dist,
                  const float* __restrict__ stats, const int* __restrict__ cnt,
                  const int2* __restrict__ list, int N, int B, int listCap) {
    int n = min(*cnt, listCap);
    int tid = threadIdx.x;
    for (int i = tid; i < n; i += blockDim.x) {
        int2 p = list[i];
        float v = dist[(size_t)p.x * N + p.y];
        out[(size_t)p.x * N + p.y] = __expf(v - stats[p.x]) * stats[B + p.x];
    }
    // scalar tail if N % 4 != 0 (N=50000 -> none), written with row baseline
    int tail = N & 3;
    for (int i = tid; i < tail * B; i += blockDim.x) {
        int b = i / tail, k = i % tail;
        out[(size_t)b * N + (N - tail) + k] = stats[2 * B + b];
    }
    if (tid == 0) out[(size_t)B * N] = 0.0f;   // ALPHA = 0.0
}

extern "C" void kernel_launch(void* const* d_in, const int* in_sizes, int n_in,
                              void* d_out, int out_size, void* d_ws, size_t ws_size,
                              hipStream_t stream) {
    const int*   edge_index = (const int*)d_in[0];   // (2,E): heads then tails
    const int*   edge_type  = (const int*)d_in[1];   // (E,)
    const int*   batch      = (const int*)d_in[2];   // (B,32,3)
    const float* ew         = (const float*)d_in[3]; // (E,)

    const int E = in_sizes[1];
    const int B = in_sizes[2] / 96;
    const int N = (out_size - 1) / B;
    float* out = (float*)d_out;

    // ws layout: dist (B*N f32) | stats (3*B f32) | cnt (int) | list (int2[])
    char* ws = (char*)d_ws;
    size_t distBytes = (size_t)B * N * sizeof(float);
    float* dist  = (float*)ws;
    float* stats = (float*)(ws + distBytes);
    int*   cnt   = (int*)(ws + distBytes + (size_t)3 * B * sizeof(float));
    size_t listOff = distBytes + (size_t)3 * B * sizeof(float) + sizeof(int);
    listOff = (listOff + 7) & ~(size_t)7;
    int2* list = (int2*)(ws + listOff);
    int listCap = (int)((ws_size - listOff) / sizeof(int2));

    // zero dist + stats + cnt in one memset (ws is poisoned 0xAA each call)
    hipMemsetAsync(d_ws, 0, listOff, stream);

    int threads = 256;
    int blocks = ((E + 3) / 4 + threads - 1) / threads;
    scatter_kernel<<<blocks, threads, 0, stream>>>(
        edge_index, edge_index + E, edge_type, ew, batch,
        dist, cnt, list, E, N, B, listCap);

    stats_kernel<<<1, 256, 0, stream>>>(dist, cnt, list, stats, N, B, listCap);

    int N4 = N / 4;
    dim3 fgrid((N4 + 255) / 256, B);
    fill_kernel<<<fgrid, 256, 0, stream>>>(out, stats, N4, B);

    fixup_kernel<<<1, 256, 0, stream>>>(out, dist, stats, cnt, list, N, B, listCap);
}

// Round 3
// 105.007 us; speedup vs baseline: 1.0012x; 1.0012x over previous
//
#include <hip/hip_runtime.h>
#include <stdint.h>

// dist[b, tails[e]] += ew[e] where heads[e]==batch[b,0,0] && etype[e]==batch[b,0,2],
// then row-softmax over N=50000. B=64, E=1e6. Expected matches ~5 total.
// Fully sparse: scatter-append matching triples, then each output block
// re-derives row stats from the tiny list and writes baseline + fixups fused.
//   M_b = max(0, max v), S_b = (N - nnz_b)*e^{-M} + sum e^{v-M}
//   unmatched out = e^{-M}/S (row constant); matched out = e^{v-M}/S.

#define B_MAX 64
#define ROW_MAX 256   // max distinct matched tails per row (expected ~0-2)

// ---------------- scatter: 4 edges/thread, LDS bloom over the 64 (h,r) keys --------
__global__ __launch_bounds__(256)
void scatter_kernel(const int* __restrict__ heads,
                    const int* __restrict__ tails,
                    const int* __restrict__ etype,
                    const float* __restrict__ ew,
                    const int* __restrict__ batch,
                    int* __restrict__ cnt,        // pre-zeroed
                    int2* __restrict__ list,      // (b, tail) per matching edge
                    float* __restrict__ wl,       // weight per matching edge
                    int E, int B, int listCap) {
    __shared__ unsigned s_keys[B_MAX];
    __shared__ unsigned s_bloom[128];            // 4096-bit bloom
    if (threadIdx.x < 128) s_bloom[threadIdx.x] = 0u;
    __syncthreads();
    if (threadIdx.x < B) {
        unsigned h = (unsigned)batch[threadIdx.x * 96 + 0];   // batch[b,0,0]
        unsigned r = (unsigned)batch[threadIdx.x * 96 + 2];   // batch[b,0,2]
        unsigned key = (h << 16) | (r & 0xFFFFu);
        s_keys[threadIdx.x] = key;
        unsigned hsh = (key * 0x9E3779B1u) >> 20;             // 12-bit hash
        atomicOr(&s_bloom[hsh >> 5], 1u << (hsh & 31));
    }
    __syncthreads();

    int base = (blockIdx.x * blockDim.x + threadIdx.x) * 4;
    if (base >= E) return;

    int h4[4], t4[4];
    if (base + 3 < E) {
        int4 hv = ((const int4*)heads)[base >> 2];
        int4 tv = ((const int4*)etype)[base >> 2];
        h4[0] = hv.x; h4[1] = hv.y; h4[2] = hv.z; h4[3] = hv.w;
        t4[0] = tv.x; t4[1] = tv.y; t4[2] = tv.z; t4[3] = tv.w;
    } else {
        for (int j = 0; j < 4; ++j) {
            int e = base + j;
            h4[j] = (e < E) ? heads[e] : -1;
            t4[j] = (e < E) ? etype[e] : -1;
        }
    }
#pragma unroll
    for (int j = 0; j < 4; ++j) {
        int e = base + j;
        if (e >= E) break;
        unsigned key = ((unsigned)h4[j] << 16) | ((unsigned)t4[j] & 0xFFFFu);
        unsigned hsh = (key * 0x9E3779B1u) >> 20;
        if (!(s_bloom[hsh >> 5] & (1u << (hsh & 31)))) continue;   // ~98.4% exit
        int tail = -1; float w = 0.0f;
        for (int b = 0; b < B; ++b) {
            if (s_keys[b] == key) {
                if (tail < 0) { tail = tails[e]; w = ew[e]; }
                int pos = atomicAdd(cnt, 1);
                if (pos < listCap) { list[pos] = make_int2(b, tail); wl[pos] = w; }
            }
        }
    }
}

// ---------------- fused stats + fill + fixup ---------------------------------------
// grid = (ceil(N4/256), B). Thread 0 of each block re-derives its row's stats
// from the tiny match list (n ~ 5 globally), then all threads write float4s.
__global__ __launch_bounds__(256)
void fill_kernel(float* __restrict__ out,
                 const int* __restrict__ cnt,
                 const int2* __restrict__ list,
                 const float* __restrict__ wl,
                 int N, int B, int listCap) {
    __shared__ int   s_tail[ROW_MAX];
    __shared__ float s_val[ROW_MAX];
    __shared__ int   s_m;
    __shared__ float s_base;
    const int b = blockIdx.y;

    if (threadIdx.x == 0) {
        int n = min(*cnt, listCap);
        int m = 0;
        for (int i = 0; i < n; ++i) {            // gather + dedupe this row's matches
            int2 p = list[i];
            if (p.x != b) continue;
            int k = -1;
            for (int j = 0; j < m; ++j) if (s_tail[j] == p.y) { k = j; break; }
            if (k >= 0) s_val[k] += wl[i];
            else if (m < ROW_MAX) { s_tail[m] = p.y; s_val[m] = wl[i]; ++m; }
        }
        float M = 0.0f;                           // zeros dominate: floor at 0
        for (int j = 0; j < m; ++j) M = fmaxf(M, s_val[j]);
        float em = __expf(-M);
        float S = (float)(N - m) * em;
        for (int j = 0; j < m; ++j) S += __expf(s_val[j] - M);
        float inv = 1.0f / S;
        for (int j = 0; j < m; ++j) s_val[j] = __expf(s_val[j] - M) * inv;
        s_m = m;
        s_base = em * inv;
    }
    __syncthreads();

    const int m = s_m;
    const float base = s_base;
    const int N4 = N >> 2;
    int i = blockIdx.x * blockDim.x + threadIdx.x;
    if (i < N4) {
        float4 v = make_float4(base, base, base, base);
        if (m > 0) {                              // block-uniform branch, usually false
            int c0 = i * 4;
            for (int j = 0; j < m; ++j) {
                unsigned d = (unsigned)(s_tail[j] - c0);
                if (d < 4u) ((float*)&v)[d] = s_val[j];
            }
        }
        ((float4*)(out + (size_t)b * N))[i] = v;
    }
    // scalar tail if N % 4 != 0 (N=50000 -> none)
    int rem = N & 3;
    if (rem && blockIdx.x == 0 && (int)threadIdx.x < rem) {
        int col = N - rem + threadIdx.x;
        float v = base;
        for (int j = 0; j < m; ++j) if (s_tail[j] == col) v = s_val[j];
        out[(size_t)b * N + col] = v;
    }
    if (b == 0 && blockIdx.x == 0 && threadIdx.x == 0)
        out[(size_t)B * N] = 0.0f;               // ALPHA = 0.0
}

extern "C" void kernel_launch(void* const* d_in, const int* in_sizes, int n_in,
                              void* d_out, int out_size, void* d_ws, size_t ws_size,
                              hipStream_t stream) {
    const int*   edge_index = (const int*)d_in[0];   // (2,E): heads then tails
    const int*   edge_type  = (const int*)d_in[1];   // (E,)
    const int*   batch      = (const int*)d_in[2];   // (B,32,3)
    const float* ew         = (const float*)d_in[3]; // (E,)

    const int E = in_sizes[1];
    const int B = in_sizes[2] / 96;
    const int N = (out_size - 1) / B;
    float* out = (float*)d_out;

    // ws layout: cnt (int, 16B-aligned pad) | list (int2[cap]) | wl (float[cap])
    char* ws = (char*)d_ws;
    int*  cnt = (int*)ws;
    const int listCap = 1 << 22;                 // 4M entries: 32MB + 16MB << 256MB ws
    int2*  list = (int2*)(ws + 16);
    float* wl   = (float*)(ws + 16 + (size_t)listCap * sizeof(int2));

    hipMemsetAsync(cnt, 0, sizeof(int), stream);

    const int threads = 256;
    const int blocks = ((E + 3) / 4 + threads - 1) / threads;
    scatter_kernel<<<blocks, threads, 0, stream>>>(
        edge_index, edge_index + E, edge_type, ew, batch,
        cnt, list, wl, E, B, listCap);

    const int N4 = N / 4;
    dim3 fgrid((N4 + threads - 1) / threads, B);
    fill_kernel<<<fgrid, threads, 0, stream>>>(out, cnt, list, wl, N, B, listCap);
}